// Round 15
// baseline (96.978 us; speedup 1.0000x reference)
//
#include <hip/hip_runtime.h>

#define E_ 15000
#define D_ 200
#define L_ 64
#define B_ 256
#define LOG2E 1.4426950408889634f

// ws layout (chunk-contiguous: chunk c = b's [16c, 16c+16)):
//   qtc @ 0      : [16][200][16] f32  qtc[c][d][bb] = emb_e[e1,d]*emb_rel[rel,d]
//   suc @ 204800 : [16][64][16]  f32  su2 = 2*(lit[e1,l]-c[l])*r[l]
//   wtc @ 270336 : [16][64][16]  f32  w'  = nfw[rel,l]*exp2(-su^2)
//   r   @ 335872 : [64] f32           r[l] = sqrt(log2e/var[l])
// RBF factorization: phi*wt = w' * exp2(su2*u - u^2), u = lit[e,l]*r[l].
#define QTC_OFF 0
#define SUC_OFF 204800
#define WTC_OFF 270336
#define R_OFF   335872

__global__ __launch_bounds__(256) void setup_k(
    const float* __restrict__ emb_e, const float* __restrict__ emb_rel,
    const float* __restrict__ nfw,   const float* __restrict__ lit,
    const float* __restrict__ c,     const float* __restrict__ var,
    const int* __restrict__ e1,      const int* __restrict__ rel,
    float* __restrict__ qtc, float* __restrict__ suc,
    float* __restrict__ wtc, float* __restrict__ r)
{
    const int b = blockIdx.x;
    const int t = threadIdx.x;
    const int ie = e1[b];
    const int ir = rel[b];
    const int cb = (b >> 4);
    const int bb = (b & 15);
    if (t < D_) qtc[cb * 3200 + t * 16 + bb] =
        emb_e[ie * D_ + t] * emb_rel[ir * D_ + t];
    if (t < L_) {
        const float rl = sqrtf(LOG2E / var[t]);
        const float su = (lit[ie * L_ + t] - c[t]) * rl;
        suc[cb * 1024 + t * 16 + bb] = 2.0f * su;
        wtc[cb * 1024 + t * 16 + bb] = nfw[ir * L_ + t] * exp2f(-su * su);
        if (b == 0) r[t] = rl;
    }
}

// 944 blocks = 59 e-tiles x 16 b-chunks, 512 threads = 8 waves.
// Waves 0-3 (half=0): d in [0,100), l in [0,32); waves 4-7: complement, same
// e-range -> per-block VMEM identical to R7's 256-thr version, 2x waves/SIMD.
// PLAIN SCALAR math (no inline asm, no ext-vector accumulators) — R7-proven
// codegen; combine unidirectional with static indices (R4-proven shape).
__global__ __launch_bounds__(512) void main_k(
    const float* __restrict__ emb_e, const float* __restrict__ lit,
    const float* __restrict__ qtc,   const float* __restrict__ suc,
    const float* __restrict__ wtc,   const float* __restrict__ r,
    float* __restrict__ out)
{
    __shared__ float qt_s[3200];       // 12.8 KB [d][16]
    __shared__ float su_s[1024];       //  4.0 KB [l][16]  (su2)
    __shared__ float wt_s[1024];       //  4.0 KB [l][16]  (w')
    __shared__ float r_s[64];
    __shared__ float comb[16][256];    // 16.0 KB half1 -> half0 partials

    // Bijective XCD swizzle: 944 = 8*118 exact (proven 10MB fetch in R7).
    const int w    = blockIdx.x;
    const int orig = (w & 7) * 118 + (w >> 3);
    const int x = orig >> 4;           // e-tile 0..58
    const int y = orig & 15;           // b-chunk 0..15

    const int tid  = threadIdx.x;
    const int el   = tid & 255;
    const int half = tid >> 8;         // wave-uniform (waves 0-3: 0, 4-7: 1)
    const int e    = x * 256 + el;
    const int ec   = (e < E_) ? e : (E_ - 1);
    const int b0   = y * 16;

    // ---- one-time coalesced staging: 21 KB L2 -> LDS (512 threads) ----
    {
        const float4* qsrc = (const float4*)qtc + y * 800;
        float4* qdst = (float4*)qt_s;
        qdst[tid] = qsrc[tid];
        if (tid < 288) qdst[512 + tid] = qsrc[512 + tid];
        if (tid < 256) ((float4*)su_s)[tid] = ((const float4*)suc)[y * 256 + tid];
        else ((float4*)wt_s)[tid - 256] = ((const float4*)wtc)[y * 256 + tid - 256];
        if (tid < 16) ((float4*)r_s)[tid] = ((const float4*)r)[tid];
    }
    __syncthreads();

    float acc[16];
    #pragma unroll
    for (int j = 0; j < 16; ++j) acc[j] = 0.0f;

    // ---- structural half: acc[bb] += emb_e[ec,d] * qt_s[d][bb] ----
    const float* ep = emb_e + (size_t)ec * D_ + 100 * half;
    #pragma unroll 2
    for (int d4 = 0; d4 < 100; d4 += 4) {
        const float4 v4 = *(const float4*)(ep + d4);
        const float va[4] = {v4.x, v4.y, v4.z, v4.w};
        #pragma unroll
        for (int k = 0; k < 4; ++k) {
            const float* qrow = qt_s + (100 * half + d4 + k) * 16;
            #pragma unroll
            for (int bb = 0; bb < 16; ++bb)
                acc[bb] = fmaf(va[k], qrow[bb], acc[bb]);
        }
    }

    // ---- RBF half (factored): acc[bb] += w'[l][bb] * exp2(su2[l][bb]*u - u^2) ----
    const float* lp = lit + (size_t)ec * L_ + 32 * half;
    #pragma unroll 2
    for (int l4 = 0; l4 < 32; l4 += 4) {
        const float4 x4 = *(const float4*)(lp + l4);
        const float xa[4] = {x4.x, x4.y, x4.z, x4.w};
        #pragma unroll
        for (int k = 0; k < 4; ++k) {
            const int   la  = 32 * half + l4 + k;
            const float u   = xa[k] * r_s[la];
            const float u2n = -u * u;
            const float* srow = su_s + la * 16;
            const float* wrow = wt_s + la * 16;
            #pragma unroll
            for (int bb = 0; bb < 16; ++bb) {
                const float a  = fmaf(srow[bb], u, u2n);
                const float ph = __builtin_amdgcn_exp2f(a);
                acc[bb] = fmaf(ph, wrow[bb], acc[bb]);
            }
        }
    }

    // ---- unidirectional combine (static indices only) ----
    if (half) {
        #pragma unroll
        for (int bb = 0; bb < 16; ++bb) comb[bb][el] = acc[bb];
    }
    __syncthreads();

    if (!half && e < E_) {
        #pragma unroll
        for (int bb = 0; bb < 16; ++bb) {
            const float z   = acc[bb] + comb[bb][el];
            const float ezn = __builtin_amdgcn_exp2f(-z * LOG2E);
            out[(size_t)(b0 + bb) * E_ + e] = __builtin_amdgcn_rcpf(1.0f + ezn);
        }
    }
}

extern "C" void kernel_launch(void* const* d_in, const int* in_sizes, int n_in,
                              void* d_out, int out_size, void* d_ws, size_t ws_size,
                              hipStream_t stream) {
    const float* emb_e   = (const float*)d_in[0];
    const float* emb_rel = (const float*)d_in[1];
    const float* nfw     = (const float*)d_in[2];
    const float* lit     = (const float*)d_in[3];
    const float* c       = (const float*)d_in[4];
    const float* var     = (const float*)d_in[5];
    const int*   e1      = (const int*)d_in[6];
    const int*   rel     = (const int*)d_in[7];
    float* out = (float*)d_out;

    char* ws = (char*)d_ws;
    float* qtc = (float*)(ws + QTC_OFF);
    float* suc = (float*)(ws + SUC_OFF);
    float* wtc = (float*)(ws + WTC_OFF);
    float* r   = (float*)(ws + R_OFF);

    setup_k<<<dim3(B_), dim3(256), 0, stream>>>(emb_e, emb_rel, nfw, lit, c, var,
                                                e1, rel, qtc, suc, wtc, r);

    main_k<<<dim3(944), dim3(512), 0, stream>>>(emb_e, lit, qtc, suc, wtc, r, out);
}